// Round 6
// baseline (81.965 us; speedup 1.0000x reference)
//
#include <hip/hip_runtime.h>
#include <math.h>

#define N1 16384
#define N2 16384
#define BLOCK 256
#define PTS 8                          // pos1 points per thread
#define I_BLOCKS (N1 / (BLOCK * PTS))  // 8 blocks along pos1
#define SLICES 128                     // pos2 slices -> 1024 blocks, 4 waves/SIMD

typedef float v2f __attribute__((ext_vector_type(2)));

// order-preserving float<->uint mapping (for atomicMin over possibly-negative g)
__device__ __forceinline__ unsigned int f2key(float f) {
    unsigned int b = __float_as_uint(f);
    return (b & 0x80000000u) ? ~b : (b | 0x80000000u);
}
__device__ __forceinline__ float key2f(unsigned int k) {
    unsigned int b = (k & 0x80000000u) ? (k & 0x7FFFFFFFu) : ~k;
    return __uint_as_float(b);
}

// Stage 1: for each pos1 point, min over one pos2 slice of
// g(q) = -2 p.q + |q|^2  (d^2 = |p|^2 + g, shift applied in stage 2).
// Inner loop processes TWO pos2 points per step in a packed float2 vector:
//   g2 = pk_fma(x2, ax2, pk_fma(y2, ay2, az2))      (2 instrs, 4 FMAs if
//   v_pk_fma_f32 forms; falls back to 4 v_fma_f32 otherwise)
//   m  = v_min3_f32(m, g2.x, g2.y)                  (1 instr for 2 mins)
// Cross-slice combine: fire-and-forget device-scope atomicMin on 64 KB keys.
__global__ __launch_bounds__(BLOCK, 4)
void nn_partial(const float2* __restrict__ pos1,
                const float4* __restrict__ pos2,   // 2 points per float4
                unsigned int* __restrict__ keys,
                unsigned int* __restrict__ ticket,
                int slice_f4) {
    const int ib = blockIdx.x;
    const int sl = blockIdx.y;
    const int t  = threadIdx.x;

    if (ib == 0 && sl == 0 && t == 0) *ticket = 0;  // init for stage 2

    const float4* __restrict__ q = pos2 + (size_t)sl * slice_f4;
    const int i0 = ib * (BLOCK * PTS) + t;

    v2f x2[PTS], y2[PTS];
    float m[PTS];
#pragma unroll
    for (int k = 0; k < PTS; ++k) {
        float2 p = pos1[i0 + k * BLOCK];
        x2[k] = (v2f){p.x, p.x};
        y2[k] = (v2f){p.y, p.y};
        m[k] = 3.4e38f;
    }

#pragma unroll 2
    for (int j = 0; j < slice_f4; ++j) {
        float4 qq = q[j];                    // uniform address, 2 pos2 points
        v2f qx = (v2f){qq.x, qq.z};
        v2f qy = (v2f){qq.y, qq.w};
        v2f ax = qx * -2.f;
        v2f ay = qy * -2.f;
        v2f az = __builtin_elementwise_fma(qx, qx, qy * qy);
#pragma unroll
        for (int k = 0; k < PTS; ++k) {
            v2f g = __builtin_elementwise_fma(
                        x2[k], ax, __builtin_elementwise_fma(y2[k], ay, az));
            m[k] = fminf(m[k], fminf(g.x, g.y));   // -> v_min3_f32
        }
    }

#pragma unroll
    for (int k = 0; k < PTS; ++k) {
        atomicMin(&keys[i0 + k * BLOCK], f2key(m[k]));  // fire-and-forget
    }
}

// Stage 2 (fused final): 64 blocks; decode key, + |p|^2, sqrt, block-sum;
// last block (ticket) reduces the 64 block sums and writes the mean.
__global__ __launch_bounds__(BLOCK)
void nn_finish(const unsigned int* __restrict__ keys,
               const float2* __restrict__ pos1,
               float* __restrict__ blocksums,
               unsigned int* __restrict__ ticket,
               float* __restrict__ out) {
    const int t = threadIdx.x;
    const int i = blockIdx.x * BLOCK + t;

    float g = key2f(keys[i]);
    float2 p = pos1[i];
    float d2 = fmaxf(fmaf(p.x, p.x, p.y * p.y) + g, 0.f);
    float sum = sqrtf(d2);

    for (int off = 32; off > 0; off >>= 1) {
        sum += __shfl_down(sum, off, 64);
    }
    __shared__ float wsum[BLOCK / 64];
    __shared__ int lastflag;
    if ((t & 63) == 0) wsum[t >> 6] = sum;
    __syncthreads();
    if (t == 0) {
        float s = 0.f;
        for (int w = 0; w < BLOCK / 64; ++w) s += wsum[w];
        blocksums[blockIdx.x] = s;
        __threadfence();
        unsigned int old = atomicAdd(ticket, 1u);
        lastflag = (old == gridDim.x - 1) ? 1 : 0;
    }
    __syncthreads();
    if (lastflag && t < 64) {
        volatile float* vb = (volatile float*)blocksums;
        float v = vb[t];
        for (int off = 32; off > 0; off >>= 1) {
            v += __shfl_down(v, off, 64);
        }
        if (t == 0) out[0] = v / (float)N1;
    }
}

extern "C" void kernel_launch(void* const* d_in, const int* in_sizes, int n_in,
                              void* d_out, int out_size, void* d_ws, size_t ws_size,
                              hipStream_t stream) {
    const float2* pos1 = (const float2*)d_in[0];
    const float4* pos2 = (const float4*)d_in[1];
    float* out = (float*)d_out;

    unsigned int* keys = (unsigned int*)d_ws;               // N1 uints (64 KB)
    float* blocksums   = (float*)(keys + N1);               // 64 floats
    unsigned int* ticket = (unsigned int*)(blocksums + 64); // 1 uint

    const int slice_f4 = (N2 / SLICES) / 2;  // float4s per slice (64)

    // init keys to +inf ordering (0xFFFFFFFF)
    hipMemsetAsync(keys, 0xFF, (size_t)N1 * sizeof(unsigned int), stream);

    dim3 grid1(I_BLOCKS, SLICES);
    nn_partial<<<grid1, BLOCK, 0, stream>>>(pos1, pos2, keys, ticket, slice_f4);
    nn_finish<<<N1 / BLOCK, BLOCK, 0, stream>>>(keys, pos1, blocksums, ticket, out);
}